// Round 8
// baseline (182.368 us; speedup 1.0000x reference)
//
#include <hip/hip_runtime.h>

#define E_EDGES 20000
#define D_DIM   128
#define NBA     136       // W2/b2 repack blocks: 128 W2 + 1 bias + 7 zero (prefetch pad)
#define NBC     184       // hw fp32->fp16 cast blocks (grid-stride)
#define SLAB_B  21504     // per-block hidden slab: 80 edges x 264B (132 h fp16 + pad)
#define N_ITEMS 3000      // 250 eg x 4 ch x 3 h-thirds

typedef _Float16 f16x8 __attribute__((ext_vector_type(8)));
typedef _Float16 f16x4 __attribute__((ext_vector_type(4)));
typedef _Float16 f16x2 __attribute__((ext_vector_type(2)));
typedef float    floatx4 __attribute__((ext_vector_type(4)));

union F8 { f16x8 v; f16x2 h2[4]; unsigned int u[4]; };
union F4 { f16x4 v; f16x2 h2[2]; unsigned int u[2]; };

__device__ __forceinline__ unsigned short f32_to_f16(float f) {
    _Float16 h = (_Float16)f;
    return __builtin_bit_cast(unsigned short, h);
}

// ---------------------------------------------------------------------------
// prep_all: (A) repack W2/b2 h-slices into fragment-major fp16 bpf (one
// h-slice per block, ~4 us); (B) grid-stride cast h_w fp32 -> fp16 hwb
// (halves the per-item A-source traffic for the stealing main kernel).
// ---------------------------------------------------------------------------
__global__ __launch_bounds__(256) void prep_all(
    const float* __restrict__ W2, const float* __restrict__ b2,
    const float* __restrict__ hw,
    uint4* __restrict__ bpf, unsigned short* __restrict__ hwb)
{
    __shared__ __align__(16) unsigned short tile[17408];   // [col][136]
    const int bx = blockIdx.x;
    const int t  = threadIdx.x;

    if (bx < NBA) {
        const int h = bx;
        if (h < 129) {
            const float* src = (h < 128) ? (W2 + (size_t)h * (D_DIM * D_DIM)) : b2;
            #pragma unroll
            for (int r = 0; r < 16; ++r) {
                const float4 v = ((const float4*)src)[r * 256 + t];
                int c   = (r * 256 + t) * 4;
                int col = c >> 7;
                int k   = c & 127;
                unsigned int u0 = f32_to_f16(v.x) | ((unsigned int)f32_to_f16(v.y) << 16);
                unsigned int u1 = f32_to_f16(v.z) | ((unsigned int)f32_to_f16(v.w) << 16);
                *(uint2*)&tile[col * 136 + k] = make_uint2(u0, u1);
            }
            __syncthreads();
            #pragma unroll
            for (int r2 = 0; r2 < 8; ++r2) {
                int cidx = r2 * 256 + t;
                int ll = cidx & 63;
                int nt = (cidx >> 6) & 1;
                int jq = (cidx >> 7) & 3;
                int ch = (cidx >> 9) & 3;
                int col = 32 * ch + 16 * nt + (ll & 15);
                int k0  = 32 * jq + 8 * (ll >> 4);
                bpf[(size_t)h * 2048 + cidx] = *(const uint4*)&tile[col * 136 + k0];
            }
        } else {
            // zero-fill pad slices so prefetch reads never feed garbage into MFMA
            #pragma unroll
            for (int r2 = 0; r2 < 8; ++r2)
                bpf[(size_t)h * 2048 + r2 * 256 + t] = make_uint4(0, 0, 0, 0);
        }
    } else {
        int i0 = (bx - NBA) * 256 + t;
        for (int i = i0; i < (E_EDGES * D_DIM) / 4; i += NBC * 256) {
            const float4 v = ((const float4*)hw)[i];
            union { unsigned short u16[4]; uint2 u2; } o;
            o.u16[0] = f32_to_f16(v.x);
            o.u16[1] = f32_to_f16(v.y);
            o.u16[2] = f32_to_f16(v.z);
            o.u16[3] = f32_to_f16(v.w);
            ((uint2*)hwb)[i] = o.u2;
        }
    }
}

// ---------------------------------------------------------------------------
// Main (Z-GEMM v10: persistent + work-stealing): grid EXACTLY 768 = 3
// blocks/CU (one permanent cohort; r6 proved this body is issue-saturated at
// 3-residency: 768 blocks ran at 64% of peak, 41.4 us — the remaining loss
// was purely the 2-cohort quantization of grid 1000 at 3/CU).
// Work = 3000 items: (eg 0..249) x (ch 0..3) x (h-third 0..2, 44 h = 11
// quads each). Blocks pop items from a global atomic counter (~3.9/block);
// item order third-major/ch-mid/eg-fast keeps concurrent blocks on the same
// 1.1 MB bpf slice (L2) and on distinct out cache lines.
// Per item: hws from prep-cast fp16 hwb; MLP slab rebuilt (10 mfma-16x16x16,
// ef/W1/b1 L2-hot); depth-4 B register prefetch; hid ds_read ping-pong;
// LDS jq-reduce then unsafeAtomicAdd into memset-zeroed out (3 h-third
// writers per element). Body register shape identical to r6 (no spill at
// bounds(256,3); tripwire: FETCH > 300 MB means spill returned).
// ---------------------------------------------------------------------------
__global__ __launch_bounds__(256, 3)
void edge_main(const uint4* __restrict__ bpf, const uint4* __restrict__ hwb,
               const float* __restrict__ ef, const float* __restrict__ W1,
               const float* __restrict__ b1, float* __restrict__ out,
               int* __restrict__ counter)
{
    __shared__ __align__(16) char slab[SLAB_B];
    __shared__ int s_id;
    const int tid = threadIdx.x;
    const int jq  = tid >> 6;                 // j-quarter, 0..3
    const int l   = tid & 63;
    const int l4  = l >> 4;
    const int lm  = l & 15;
    const f16x8* bpf8 = (const f16x8*)bpf;

    for (;;) {
        __syncthreads();                      // guards slab + s_id reuse
        if (tid == 0) s_id = atomicAdd(counter, 1);
        __syncthreads();
        const int id = s_id;
        if (id >= N_ITEMS) break;

        // id = third*1000 + ch*250 + eg
        const int third = id / 1000;
        const int r1    = id - third * 1000;
        const int ch    = r1 / 250;
        const int eg    = r1 - ch * 250;
        const int e0    = eg * 80;
        const int qs    = third * 11;         // quads [qs, qs+11); h = 4q..
        const int cbase = ch * 512 + jq * 128 + l;

        // ---- resident h_w A-source (fp16, prep-cast) ----
        F8 hws[5];
        #pragma unroll
        for (int m = 0; m < 5; ++m)
            hws[m].v = ((const F8*)hwb)[(e0 + 16 * m + lm) * 16 + 4 * jq + l4].v;

        // ---- depth-4 B register prefetch prologue (h0 = 44*third, mult of 4) ----
        f16x8 B[4][2];
        auto loadB = [&](int h, f16x8 (&Bq)[2]) {
            const f16x8* p = bpf8 + (size_t)h * 2048 + cbase;
            Bq[0] = p[0];
            Bq[1] = p[64];                    // 2 x 1KB contiguous per wave
        };
        const int h0 = 4 * qs;
        loadB(h0 + 0, B[0]);
        loadB(h0 + 1, B[1]);
        loadB(h0 + 2, B[2]);
        loadB(h0 + 3, B[3]);

        // ---- rebuild edge-MLP slab: hidden = relu(ef@W1+b1) fp16 [80][132] ----
        {
            F4 A[5];
            #pragma unroll
            for (int m = 0; m < 5; ++m) {
                const float4 q4 = *(const float4*)(ef + (size_t)(e0 + 16 * m + lm) * 16 + 4 * l4);
                A[m].h2[0] = (f16x2){(_Float16)q4.x, (_Float16)q4.y};
                A[m].h2[1] = (f16x2){(_Float16)q4.z, (_Float16)q4.w};
            }
            F4 Bw[2];
            float bv[2];
            #pragma unroll
            for (int nn = 0; nn < 2; ++nn) {
                const int col = jq * 32 + nn * 16 + lm;
                float w0 = W1[(4 * l4 + 0) * 128 + col];
                float w1 = W1[(4 * l4 + 1) * 128 + col];
                float w2 = W1[(4 * l4 + 2) * 128 + col];
                float w3 = W1[(4 * l4 + 3) * 128 + col];
                Bw[nn].h2[0] = (f16x2){(_Float16)w0, (_Float16)w1};
                Bw[nn].h2[1] = (f16x2){(_Float16)w2, (_Float16)w3};
                bv[nn] = b1[col];
            }
            #pragma unroll
            for (int m = 0; m < 5; ++m) {
                floatx4 H0 = (floatx4){bv[0], bv[0], bv[0], bv[0]};
                floatx4 H1 = (floatx4){bv[1], bv[1], bv[1], bv[1]};
                H0 = __builtin_amdgcn_mfma_f32_16x16x16f16(A[m].v, Bw[0].v, H0, 0, 0, 0);
                H1 = __builtin_amdgcn_mfma_f32_16x16x16f16(A[m].v, Bw[1].v, H1, 0, 0, 0);
                #pragma unroll
                for (int r = 0; r < 4; ++r) {
                    const int e = 16 * m + 4 * l4 + r;      // D: row=4*l4+r, col=lm
                    *(unsigned short*)(slab + e * 264 + (jq * 32 + lm) * 2) =
                        f32_to_f16(fmaxf(H0[r], 0.f));
                    *(unsigned short*)(slab + e * 264 + (jq * 32 + 16 + lm) * 2) =
                        f32_to_f16(fmaxf(H1[r], 0.f));
                }
            }
            if (tid < 80) {
                *(unsigned int*)(slab + tid * 264 + 256) = 0x00003C00u; // h=128:1.0, 129:0
                *(unsigned int*)(slab + tid * 264 + 260) = 0u;          // h=130,131: 0
            }
        }

        floatx4 C[5][2];
        #pragma unroll
        for (int m = 0; m < 5; ++m)
            #pragma unroll
            for (int nt = 0; nt < 2; ++nt)
                C[m][nt] = (floatx4){0.f, 0.f, 0.f, 0.f};

        __syncthreads();    // slab ready

        auto doH = [&](int h, const uint2 (&hid)[5]) {
            const int hh = h & 3;
            #pragma unroll
            for (int m = 0; m < 5; ++m) {
                unsigned int s   = (hh < 2) ? hid[m].x : hid[m].y;
                unsigned int sel = (hh & 1) ? 0x03020302u : 0x01000100u;
                f16x2 d = __builtin_bit_cast(f16x2, __builtin_amdgcn_perm(0u, s, sel));
                F8 a;
                #pragma unroll
                for (int i = 0; i < 4; ++i) a.h2[i] = hws[m].h2[i] * d;
                C[m][0] = __builtin_amdgcn_mfma_f32_16x16x32_f16(a.v, B[hh][0], C[m][0], 0, 0, 0);
                C[m][1] = __builtin_amdgcn_mfma_f32_16x16x32_f16(a.v, B[hh][1], C[m][1], 0, 0, 0);
            }
            loadB(h + 4, B[hh]);              // refill (max h+4 = 4*qs+47 <= 135 < 136)
        };
        auto readHid = [&](int q, uint2 (&hid)[5]) {
            #pragma unroll
            for (int m = 0; m < 5; ++m)       // broadcast ds_read_b64 (l4 ignored)
                hid[m] = *(const uint2*)(slab + (16 * m + lm) * 264 + q * 8);
        };

        // 11 quads: 5 ping-pong pairs + 1 tail quad
        uint2 hid0[5], hid1[5];
        readHid(qs, hid0);
        #pragma unroll 1
        for (int q = qs; q + 2 < qs + 11; q += 2) {
            readHid(q + 1, hid1);             // prefetch next quad's hid
            doH(4 * q + 0, hid0);
            doH(4 * q + 1, hid0);
            doH(4 * q + 2, hid0);
            doH(4 * q + 3, hid0);
            readHid(q + 2, hid0);             // q+2 <= qs+10 <= 32: valid row bytes
            doH(4 * q + 4, hid1);
            doH(4 * q + 5, hid1);
            doH(4 * q + 6, hid1);
            doH(4 * q + 7, hid1);
        }
        {
            const int qT = qs + 10;           // tail quad, hid0 from last readHid
            doH(4 * qT + 0, hid0);
            doH(4 * qT + 1, hid0);
            doH(4 * qT + 2, hid0);
            doH(4 * qT + 3, hid0);
        }

        // epilogue: reduce 4 jq partials via LDS (reuse slab), then atomic
        // fadd into zeroed out (3 h-third writers). C/D: col=lane&15, row=4*(lane>>4)+r.
        float* red = (float*)slab;
        #pragma unroll 1
        for (int src = 1; src < 4; ++src) {
            __syncthreads();
            if (jq == src) {
                #pragma unroll
                for (int m = 0; m < 5; ++m)
                    #pragma unroll
                    for (int nt = 0; nt < 2; ++nt)
                        #pragma unroll
                        for (int r = 0; r < 4; ++r)
                            red[((m * 2 + nt) * 4 + r) * 64 + l] = C[m][nt][r];
            }
            __syncthreads();
            if (jq == 0) {
                #pragma unroll
                for (int m = 0; m < 5; ++m)
                    #pragma unroll
                    for (int nt = 0; nt < 2; ++nt)
                        #pragma unroll
                        for (int r = 0; r < 4; ++r)
                            C[m][nt][r] += red[((m * 2 + nt) * 4 + r) * 64 + l];
            }
        }
        if (jq == 0) {
            #pragma unroll
            for (int m = 0; m < 5; ++m)
                #pragma unroll
                for (int nt = 0; nt < 2; ++nt)
                    #pragma unroll
                    for (int r = 0; r < 4; ++r)
                        unsafeAtomicAdd(out + (size_t)(e0 + 16 * m + 4 * l4 + r) * D_DIM
                                            + 32 * ch + 16 * nt + lm,
                                        C[m][nt][r]);
        }
    }
}

// ---------------------------------------------------------------------------
extern "C" void kernel_launch(void* const* d_in, const int* in_sizes, int n_in,
                              void* d_out, int out_size, void* d_ws, size_t ws_size,
                              hipStream_t stream) {
    // inputs: h_v, h_w, edge_features, W1, b1, W2, b2 (fp32; h_v unused)
    const float* h_w = (const float*)d_in[1];
    const float* ef  = (const float*)d_in[2];
    const float* W1  = (const float*)d_in[3];
    const float* b1  = (const float*)d_in[4];
    const float* W2  = (const float*)d_in[5];
    const float* b2  = (const float*)d_in[6];
    float* out = (float*)d_out;

    char* ws = (char*)d_ws;
    uint4*          bpf     = (uint4*)ws;                         // 4,456,448 B
    unsigned short* hwb     = (unsigned short*)(ws + 4456448);    // 5,120,000 B
    int*            counter = (int*)(ws + 4456448 + 5120000);     // 4 B
    // total ws use: 9,576,452 B

    (void)hipMemsetAsync(out, 0, (size_t)E_EDGES * D_DIM * sizeof(float), stream);
    (void)hipMemsetAsync(counter, 0, sizeof(int), stream);
    hipLaunchKernelGGL(prep_all, dim3(NBA + NBC), dim3(256), 0, stream,
                       W2, b2, h_w, bpf, hwb);
    hipLaunchKernelGGL(edge_main, dim3(768), dim3(256), 0, stream,
                       bpf, (const uint4*)hwb, ef, W1, b1, out, counter);
}

// Round 9
// 168.189 us; speedup vs baseline: 1.0843x; 1.0843x over previous
//
#include <hip/hip_runtime.h>

#define E_EDGES 20000
#define D_DIM   128
#define NBA     136       // W2/b2 repack blocks: 128 W2 + 1 bias + 7 zero (prefetch pad)
#define NBC     184       // hw fp32->fp16 cast blocks (grid-stride)
#define SLAB_B  21504     // per-block hidden slab: 80 edges x 264B (132 h fp16 + pad)

typedef _Float16 f16x8 __attribute__((ext_vector_type(8)));
typedef _Float16 f16x4 __attribute__((ext_vector_type(4)));
typedef _Float16 f16x2 __attribute__((ext_vector_type(2)));
typedef float    floatx4 __attribute__((ext_vector_type(4)));

union F8 { f16x8 v; f16x2 h2[4]; unsigned int u[4]; };
union F4 { f16x4 v; f16x2 h2[2]; unsigned int u[2]; };

__device__ __forceinline__ unsigned short f32_to_f16(float f) {
    _Float16 h = (_Float16)f;
    return __builtin_bit_cast(unsigned short, h);
}

// ---------------------------------------------------------------------------
// prep_all: (A) repack W2/b2 h-slices into fragment-major fp16 bpf (one
// h-slice per block, ~4 us); (B) grid-stride cast h_w fp32 -> fp16 hwb
// (h_w is now read by TWO h-half blocks; fp16 halves that re-read).
// ---------------------------------------------------------------------------
__global__ __launch_bounds__(256) void prep_all(
    const float* __restrict__ W2, const float* __restrict__ b2,
    const float* __restrict__ hw,
    uint4* __restrict__ bpf, unsigned short* __restrict__ hwb)
{
    __shared__ __align__(16) unsigned short tile[17408];   // [col][136]
    const int bx = blockIdx.x;
    const int t  = threadIdx.x;

    if (bx < NBA) {
        const int h = bx;
        if (h < 129) {
            const float* src = (h < 128) ? (W2 + (size_t)h * (D_DIM * D_DIM)) : b2;
            #pragma unroll
            for (int r = 0; r < 16; ++r) {
                const float4 v = ((const float4*)src)[r * 256 + t];
                int c   = (r * 256 + t) * 4;
                int col = c >> 7;
                int k   = c & 127;
                unsigned int u0 = f32_to_f16(v.x) | ((unsigned int)f32_to_f16(v.y) << 16);
                unsigned int u1 = f32_to_f16(v.z) | ((unsigned int)f32_to_f16(v.w) << 16);
                *(uint2*)&tile[col * 136 + k] = make_uint2(u0, u1);
            }
            __syncthreads();
            #pragma unroll
            for (int r2 = 0; r2 < 8; ++r2) {
                int cidx = r2 * 256 + t;
                int ll = cidx & 63;
                int nt = (cidx >> 6) & 1;
                int jq = (cidx >> 7) & 3;
                int ch = (cidx >> 9) & 3;
                int col = 32 * ch + 16 * nt + (ll & 15);
                int k0  = 32 * jq + 8 * (ll >> 4);
                bpf[(size_t)h * 2048 + cidx] = *(const uint4*)&tile[col * 136 + k0];
            }
        } else {
            // zero-fill pad slices so prefetch reads never feed garbage into MFMA
            #pragma unroll
            for (int r2 = 0; r2 < 8; ++r2)
                bpf[(size_t)h * 2048 + r2 * 256 + t] = make_uint4(0, 0, 0, 0);
        }
    } else {
        int i0 = (bx - NBA) * 256 + t;
        for (int i = i0; i < (E_EDGES * D_DIM) / 4; i += NBC * 256) {
            const float4 v = ((const float4*)hw)[i];
            union { unsigned short u16[4]; uint2 u2; } o;
            o.u16[0] = f32_to_f16(v.x);
            o.u16[1] = f32_to_f16(v.y);
            o.u16[2] = f32_to_f16(v.z);
            o.u16[3] = f32_to_f16(v.w);
            ((uint2*)hwb)[i] = o.u2;
        }
    }
}

// ---------------------------------------------------------------------------
// Main (Z-GEMM v11: static h-half split): 2000 blocks x 256 threads, 3/CU.
// r8 lesson: fine items (44-h thirds, stolen) pay the full prologue+epilogue
// per item (~13 us measured) -> 99.7 us. r6 lesson: the body at 3-residency
// runs at 64% of MFMA peak; its 82.7 us wall was pure 2-cohort quantization
// (1000 blocks into 768 slots = 2 x 41.4). Fix: HALVE the block (not third):
// block = (eg 0..249) x (ch 0..3) x (hh 0..1), h-half = 64 or 68 h-steps.
// Overhead paid 2x, and 2000 ~22us blocks pack continuously into 768 slots:
// wall ~ 2000*23/768 ~ 60 us. bx bits 0-2 = (ch,hh) -> each XCD pinned to a
// fixed ~540 KB bpf slice (L2-resident); eg-consecutive blocks same XCD.
// Body identical to r6 (no spill at bounds(256,3)): depth-4 B register
// prefetch, hid ds_read ping-pong, fused MLP slab rebuild, hws from fp16 hwb.
// Epilogue: LDS jq-reduce then unsafeAtomicAdd into memset-zeroed out
// (2 h-half writers/element). Tripwire: FETCH > 300 MB = spill returned.
// ---------------------------------------------------------------------------
__global__ __launch_bounds__(256, 3)
void edge_main(const uint4* __restrict__ bpf, const uint4* __restrict__ hwb,
               const float* __restrict__ ef, const float* __restrict__ W1,
               const float* __restrict__ b1, float* __restrict__ out)
{
    __shared__ __align__(16) char slab[SLAB_B];
    const int bx  = blockIdx.x;
    const int ch  = bx & 3;                   // col-quarter
    const int hh  = (bx >> 2) & 1;            // h-half: 0 -> h[0,64), 1 -> h[64,132)
    const int eg  = bx >> 3;                  // 0..249
    const int tid = threadIdx.x;
    const int jq  = tid >> 6;                 // j-quarter, 0..3
    const int l   = tid & 63;
    const int l4  = l >> 4;
    const int lm  = l & 15;
    const int e0  = eg * 80;                  // 250*80 = 20000 exact, no masks
    const int cbase = ch * 512 + jq * 128 + l;
    const f16x8* bpf8 = (const f16x8*)bpf;

    // ---- resident h_w A-source (fp16, prep-cast): issue at kernel entry ----
    F8 hws[5];
    #pragma unroll
    for (int m = 0; m < 5; ++m)
        hws[m].v = ((const F8*)hwb)[(e0 + 16 * m + lm) * 16 + 4 * jq + l4].v;

    // ---- depth-4 B register prefetch prologue (h0 = 64*hh, multiple of 4) ----
    f16x8 B[4][2];
    auto loadB = [&](int h, f16x8 (&Bq)[2]) {
        const f16x8* p = bpf8 + (size_t)h * 2048 + cbase;
        Bq[0] = p[0];
        Bq[1] = p[64];                        // 2 x 1KB contiguous per wave
    };
    const int h0 = hh * 64;
    loadB(h0 + 0, B[0]);
    loadB(h0 + 1, B[1]);
    loadB(h0 + 2, B[2]);
    loadB(h0 + 3, B[3]);

    // ---- fused edge-MLP: hidden = relu(ef @ W1 + b1) -> slab fp16 [80][132] ----
    // A: ef rows (K=16 = edge_dim, one MFMA). A-frag: row=l&15, k=4*l4+i.
    // B: W1 cols. Wave jq covers h-cols [32jq, 32jq+32) as two 16-col tiles.
    {
        F4 A[5];
        #pragma unroll
        for (int m = 0; m < 5; ++m) {
            const float4 q4 = *(const float4*)(ef + (size_t)(e0 + 16 * m + lm) * 16 + 4 * l4);
            A[m].h2[0] = (f16x2){(_Float16)q4.x, (_Float16)q4.y};
            A[m].h2[1] = (f16x2){(_Float16)q4.z, (_Float16)q4.w};
        }
        F4 Bw[2];
        float bv[2];
        #pragma unroll
        for (int nn = 0; nn < 2; ++nn) {
            const int col = jq * 32 + nn * 16 + lm;
            float w0 = W1[(4 * l4 + 0) * 128 + col];
            float w1 = W1[(4 * l4 + 1) * 128 + col];
            float w2 = W1[(4 * l4 + 2) * 128 + col];
            float w3 = W1[(4 * l4 + 3) * 128 + col];
            Bw[nn].h2[0] = (f16x2){(_Float16)w0, (_Float16)w1};
            Bw[nn].h2[1] = (f16x2){(_Float16)w2, (_Float16)w3};
            bv[nn] = b1[col];
        }
        #pragma unroll
        for (int m = 0; m < 5; ++m) {
            floatx4 H0 = (floatx4){bv[0], bv[0], bv[0], bv[0]};
            floatx4 H1 = (floatx4){bv[1], bv[1], bv[1], bv[1]};
            H0 = __builtin_amdgcn_mfma_f32_16x16x16f16(A[m].v, Bw[0].v, H0, 0, 0, 0);
            H1 = __builtin_amdgcn_mfma_f32_16x16x16f16(A[m].v, Bw[1].v, H1, 0, 0, 0);
            #pragma unroll
            for (int r = 0; r < 4; ++r) {
                const int e = 16 * m + 4 * l4 + r;          // D: row=4*l4+r, col=lm
                *(unsigned short*)(slab + e * 264 + (jq * 32 + lm) * 2) =
                    f32_to_f16(fmaxf(H0[r], 0.f));
                *(unsigned short*)(slab + e * 264 + (jq * 32 + 16 + lm) * 2) =
                    f32_to_f16(fmaxf(H1[r], 0.f));
            }
        }
        if (tid < 80) {
            *(unsigned int*)(slab + tid * 264 + 256) = 0x00003C00u; // h=128: 1.0, h=129: 0
            *(unsigned int*)(slab + tid * 264 + 260) = 0u;          // h=130,131: 0
        }
    }

    floatx4 C[5][2];
    #pragma unroll
    for (int m = 0; m < 5; ++m)
        #pragma unroll
        for (int nt = 0; nt < 2; ++nt)
            C[m][nt] = (floatx4){0.f, 0.f, 0.f, 0.f};

    __syncthreads();    // slab (hidden) complete; only barrier before epilogue

    auto doH = [&](int h, const uint2 (&hid)[5]) {
        const int hh4 = h & 3;
        #pragma unroll
        for (int m = 0; m < 5; ++m) {
            unsigned int s   = (hh4 < 2) ? hid[m].x : hid[m].y;
            unsigned int sel = (hh4 & 1) ? 0x03020302u : 0x01000100u;
            f16x2 d = __builtin_bit_cast(f16x2, __builtin_amdgcn_perm(0u, s, sel));
            F8 a;
            #pragma unroll
            for (int i = 0; i < 4; ++i) a.h2[i] = hws[m].h2[i] * d;
            C[m][0] = __builtin_amdgcn_mfma_f32_16x16x32_f16(a.v, B[hh4][0], C[m][0], 0, 0, 0);
            C[m][1] = __builtin_amdgcn_mfma_f32_16x16x32_f16(a.v, B[hh4][1], C[m][1], 0, 0, 0);
        }
        loadB(h + 4, B[hh4]);                 // refill (max h+4 = 135 < 136)
    };
    auto readHid = [&](int q, uint2 (&hid)[5]) {
        #pragma unroll
        for (int m = 0; m < 5; ++m)           // broadcast ds_read_b64 (l4 ignored)
            hid[m] = *(const uint2*)(slab + (16 * m + lm) * 264 + q * 8);
    };

    // h-half quad range: hh=0 -> q in [0,16) (h 0..63, 8 even pairs);
    // hh=1 -> q in [16,33) (h 64..131, 8 pairs + tail quad 32 = bias+pads)
    const int qs = hh ? 16 : 0;
    const int qe = hh ? 33 : 16;

    uint2 hid0[5], hid1[5];
    readHid(qs, hid0);
    int q = qs;
    #pragma unroll 1
    for (; q + 2 <= qe; q += 2) {             // quad pair q, q+1
        readHid(q + 1, hid1);                 // prefetch next quad's hid
        doH(4 * q + 0, hid0);
        doH(4 * q + 1, hid0);
        doH(4 * q + 2, hid0);
        doH(4 * q + 3, hid0);
        readHid(q + 2, hid0);                 // q+2 <= 32: row bytes 256..263 exist
        doH(4 * q + 4, hid1);
        doH(4 * q + 5, hid1);
        doH(4 * q + 6, hid1);
        doH(4 * q + 7, hid1);
    }
    if (q < qe) {                             // hh=1 tail: q=32, h=128..131 (bias+pads)
        doH(128, hid0);
        doH(129, hid0);
        doH(130, hid0);
        doH(131, hid0);
    }

    // epilogue: reduce the 4 jq partials in-block via LDS (reuse slab: 10240B),
    // then atomic fadd into zeroed out (2 h-half writers per element).
    // C/D layout: col = lane&15, row = 4*(lane>>4)+r.
    float* red = (float*)slab;
    #pragma unroll 1
    for (int src = 1; src < 4; ++src) {
        __syncthreads();
        if (jq == src) {
            #pragma unroll
            for (int m = 0; m < 5; ++m)
                #pragma unroll
                for (int nt = 0; nt < 2; ++nt)
                    #pragma unroll
                    for (int r = 0; r < 4; ++r)
                        red[((m * 2 + nt) * 4 + r) * 64 + l] = C[m][nt][r];
        }
        __syncthreads();
        if (jq == 0) {
            #pragma unroll
            for (int m = 0; m < 5; ++m)
                #pragma unroll
                for (int nt = 0; nt < 2; ++nt)
                    #pragma unroll
                    for (int r = 0; r < 4; ++r)
                        C[m][nt][r] += red[((m * 2 + nt) * 4 + r) * 64 + l];
        }
    }
    if (jq == 0) {
        #pragma unroll
        for (int m = 0; m < 5; ++m)
            #pragma unroll
            for (int nt = 0; nt < 2; ++nt)
                #pragma unroll
                for (int r = 0; r < 4; ++r)
                    unsafeAtomicAdd(out + (size_t)(e0 + 16 * m + 4 * l4 + r) * D_DIM
                                        + 32 * ch + 16 * nt + lm,
                                    C[m][nt][r]);
    }
}

// ---------------------------------------------------------------------------
extern "C" void kernel_launch(void* const* d_in, const int* in_sizes, int n_in,
                              void* d_out, int out_size, void* d_ws, size_t ws_size,
                              hipStream_t stream) {
    // inputs: h_v, h_w, edge_features, W1, b1, W2, b2 (fp32; h_v unused)
    const float* h_w = (const float*)d_in[1];
    const float* ef  = (const float*)d_in[2];
    const float* W1  = (const float*)d_in[3];
    const float* b1  = (const float*)d_in[4];
    const float* W2  = (const float*)d_in[5];
    const float* b2  = (const float*)d_in[6];
    float* out = (float*)d_out;

    char* ws = (char*)d_ws;
    uint4*          bpf = (uint4*)ws;                         // 4,456,448 B
    unsigned short* hwb = (unsigned short*)(ws + 4456448);    // 5,120,000 B
    // total ws use: 9,576,448 B

    // out is accumulated atomically by the two h-half blocks -> zero it first
    (void)hipMemsetAsync(out, 0, (size_t)E_EDGES * D_DIM * sizeof(float), stream);
    hipLaunchKernelGGL(prep_all, dim3(NBA + NBC), dim3(256), 0, stream,
                       W2, b2, h_w, bpf, hwb);
    hipLaunchKernelGGL(edge_main, dim3(2000), dim3(256), 0, stream,
                       bpf, (const uint4*)hwb, ef, W1, b1, out);
}